// Round 5
// baseline (241.042 us; speedup 1.0000x reference)
//
#include <hip/hip_runtime.h>
#include <math.h>

typedef unsigned short u16;
typedef unsigned int   u32;

#define B_       64
#define NN_      64
#define HL_      50
#define IN_DIM   384
#define POS_DIM  64
#define ATT_DIM  256
#define NEWS_DIM 448   // IN_DIM + POS_DIM

typedef __attribute__((ext_vector_type(8))) short short8;   // bf16x8 MFMA frag
typedef __attribute__((ext_vector_type(4))) float f32x4;    // MFMA acc

__device__ __forceinline__ u16 f2bf(float f) {
    union { float f; u32 i; } v; v.f = f;
    u32 r = v.i + 0x7fffu + ((v.i >> 16) & 1u);   // RNE
    return (u16)(r >> 16);
}
// pack 8 consecutive f32 -> bf16x8 fragment
__device__ __forceinline__ short8 pack8(const float* p) {
    union { short8 v; u16 e[8]; } r;
#pragma unroll
    for (int j = 0; j < 8; j++) r.e[j] = f2bf(p[j]);
    return r.v;
}

// ---------------- K1: pn = newsv(4096x384) . W1[:, :384]^T + b1 -> f32 scratch
// (pos_emb[0]==0 exactly, so nf tail contributes nothing: K=384.)
__global__ __launch_bounds__(64) void gemm_pn(
    const float* __restrict__ A, const float* __restrict__ W,
    const float* __restrict__ bias, float* __restrict__ pn)
{
    int lane = threadIdx.x;
    int m = lane & 15, q = lane >> 4;
    int r0 = blockIdx.x * 64, c0 = blockIdx.y * 64;
    f32x4 acc[4][4];
#pragma unroll
    for (int a = 0; a < 4; a++)
#pragma unroll
        for (int b = 0; b < 4; b++) acc[a][b] = (f32x4){0.f, 0.f, 0.f, 0.f};

    const float* Ap = A + (size_t)(r0 + m) * IN_DIM + q * 8;
    const float* Wp = W + (size_t)(c0 + m) * (2 * NEWS_DIM) + q * 8;

    for (int k = 0; k < IN_DIM; k += 32) {
        short8 af[4], wf[4];
#pragma unroll
        for (int rt = 0; rt < 4; rt++) af[rt] = pack8(Ap + rt * 16 * IN_DIM + k);
#pragma unroll
        for (int ct = 0; ct < 4; ct++) wf[ct] = pack8(Wp + ct * 16 * (2 * NEWS_DIM) + k);
#pragma unroll
        for (int rt = 0; rt < 4; rt++)
#pragma unroll
            for (int ct = 0; ct < 4; ct++)
                acc[rt][ct] = __builtin_amdgcn_mfma_f32_16x16x32_bf16(
                    af[rt], wf[ct], acc[rt][ct], 0, 0, 0);
    }
    // C/D layout: col = lane&15, row = (lane>>4)*4 + i  [m89]
#pragma unroll
    for (int rt = 0; rt < 4; rt++)
#pragma unroll
        for (int ct = 0; ct < 4; ct++)
#pragma unroll
            for (int i = 0; i < 4; i++) {
                int gr = r0 + rt * 16 + q * 4 + i;
                int gc = c0 + ct * 16 + m;
                pn[(size_t)gr * ATT_DIM + gc] = acc[rt][ct][i] + bias[gc];
            }
}

// ---------------- K2: plT = (virtual lf)(3200x448) . W1[:, 448:]^T -> f32, transposed
// lf row r=(b*50+h): d<384 -> logv[r*384+d]; d>=384 -> pos[(1+h)*64 + d-384].
__global__ __launch_bounds__(64) void gemm_plT(
    const float* __restrict__ logv, const float* __restrict__ pos,
    const float* __restrict__ W, float* __restrict__ plT)
{
    int lane = threadIdx.x;
    int m = lane & 15, q = lane >> 4;
    int r0 = blockIdx.x * 64, c0 = blockIdx.y * 64;
    f32x4 acc[4][4];
#pragma unroll
    for (int a = 0; a < 4; a++)
#pragma unroll
        for (int b = 0; b < 4; b++) acc[a][b] = (f32x4){0.f, 0.f, 0.f, 0.f};

    const float* Lp[4]; const float* Pp[4];
#pragma unroll
    for (int rt = 0; rt < 4; rt++) {
        int r = r0 + m + rt * 16;
        int h = r % HL_;
        Lp[rt] = logv + (size_t)r * IN_DIM + q * 8;
        Pp[rt] = pos + (size_t)(1 + h) * POS_DIM + q * 8;
    }
    const float* Wp = W + (size_t)(c0 + m) * (2 * NEWS_DIM) + NEWS_DIM + q * 8;

    for (int k = 0; k < IN_DIM; k += 32) {       // logv part
        short8 af[4], wf[4];
#pragma unroll
        for (int rt = 0; rt < 4; rt++) af[rt] = pack8(Lp[rt] + k);
#pragma unroll
        for (int ct = 0; ct < 4; ct++) wf[ct] = pack8(Wp + ct * 16 * (2 * NEWS_DIM) + k);
#pragma unroll
        for (int rt = 0; rt < 4; rt++)
#pragma unroll
            for (int ct = 0; ct < 4; ct++)
                acc[rt][ct] = __builtin_amdgcn_mfma_f32_16x16x32_bf16(
                    af[rt], wf[ct], acc[rt][ct], 0, 0, 0);
    }
#pragma unroll
    for (int k = IN_DIM; k < NEWS_DIM; k += 32) { // pos part (k=384,416)
        short8 af[4], wf[4];
#pragma unroll
        for (int rt = 0; rt < 4; rt++) af[rt] = pack8(Pp[rt] + (k - IN_DIM));
#pragma unroll
        for (int ct = 0; ct < 4; ct++) wf[ct] = pack8(Wp + ct * 16 * (2 * NEWS_DIM) + k);
#pragma unroll
        for (int rt = 0; rt < 4; rt++)
#pragma unroll
            for (int ct = 0; ct < 4; ct++)
                acc[rt][ct] = __builtin_amdgcn_mfma_f32_16x16x32_bf16(
                    af[rt], wf[ct], acc[rt][ct], 0, 0, 0);
    }
#pragma unroll
    for (int rt = 0; rt < 4; rt++)
#pragma unroll
        for (int ct = 0; ct < 4; ct++)
#pragma unroll
            for (int i = 0; i < 4; i++) {
                int gr = r0 + rt * 16 + q * 4 + i;      // row in [0,3200)
                int gc = c0 + ct * 16 + m;              // a in [0,256)
                int bb = gr / HL_, hh = gr - bb * HL_;
                plT[(size_t)(bb * ATT_DIM + gc) * HL_ + hh] = acc[rt][ct][i];
            }
}

// ---------------- K3: logits -> masked softmax. One wave per (b,n), lane = h.
__global__ __launch_bounds__(256) void attn_k(
    const float* __restrict__ pn, const float* __restrict__ plT,
    const float* __restrict__ w2, const int* __restrict__ lmask,
    float* __restrict__ attn)
{
    int lane = threadIdx.x & 63;
    int wid = (int)(threadIdx.x >> 6);
    int gid = blockIdx.x * 4 + wid;            // b*64 + n
    int b = gid >> 6;
    int hl = (lane < HL_) ? lane : (HL_ - 1);  // clamp: keep reads in-bounds
    const float* pr = pn + (size_t)gid * ATT_DIM;        // b1 folded in
    const float* pl = plT + (size_t)b * ATT_DIM * HL_;
    float acc = 0.f;
    for (int a = 0; a < ATT_DIM; a++) {
        float x = pr[a] + pl[a * HL_ + hl];
        acc = __builtin_fmaf(tanhf(x), w2[a], acc);
    }
    int mv = (lane < HL_) ? lmask[b * HL_ + lane] : 0;
    float logit = mv ? acc : -1e9f;            // b2 dropped: softmax-invariant
    float mx = logit;
#pragma unroll
    for (int o = 32; o > 0; o >>= 1) mx = fmaxf(mx, __shfl_xor(mx, o));
    float e = expf(logit - mx);
    float s = e;
#pragma unroll
    for (int o = 32; o > 0; o >>= 1) s += __shfl_xor(s, o);
    attn[(size_t)gid * 64 + lane] = e / s;
}

// ---------------- K4: out[b,n,:] = sum_h attn[b,n,h] * lf[b,h,:]  (f32 stores)
// Virtual lf staged in LDS as packed bf16 pairs. Block = (b, 16 n's).
__global__ __launch_bounds__(256) void out_k(
    const float* __restrict__ logv, const float* __restrict__ pos,
    const float* __restrict__ attn, float* __restrict__ out)
{
    __shared__ __align__(16) u32 lf_s[HL_ * NEWS_DIM / 2];  // 224 u32/row, 44800 B
    __shared__ float at_s[64];
    int tid = threadIdx.x;
    int b = blockIdx.y, n0 = blockIdx.x * 16;

    const float4* Ls = (const float4*)(logv + (size_t)b * HL_ * IN_DIM);
    for (int i = tid; i < HL_ * IN_DIM / 4; i += 256) {    // 4800 float4 chunks
        int h = i / (IN_DIM / 4), c = i - h * (IN_DIM / 4);
        float4 v = Ls[i];
        u32* dst = lf_s + h * (NEWS_DIM / 2) + c * 2;
        dst[0] = (u32)f2bf(v.x) | ((u32)f2bf(v.y) << 16);
        dst[1] = (u32)f2bf(v.z) | ((u32)f2bf(v.w) << 16);
    }
    for (int i = tid; i < HL_ * POS_DIM / 4; i += 256) {   // 800 float4 chunks
        int h = i / (POS_DIM / 4), c = i - h * (POS_DIM / 4);
        float4 v = *(const float4*)(pos + (size_t)(1 + h) * POS_DIM + c * 4);
        u32* dst = lf_s + h * (NEWS_DIM / 2) + IN_DIM / 2 + c * 2;
        dst[0] = (u32)f2bf(v.x) | ((u32)f2bf(v.y) << 16);
        dst[1] = (u32)f2bf(v.z) | ((u32)f2bf(v.w) << 16);
    }
    __syncthreads();

    for (int ni = 0; ni < 16; ni++) {
        int gid = b * 64 + (n0 + ni);
        if (tid < 64) at_s[tid] = attn[(size_t)gid * 64 + tid];
        __syncthreads();
        if (tid < 224) {                                   // d = 2*tid, 2*tid+1
            float a0 = 0.f, a1 = 0.f;
#pragma unroll 5
            for (int h = 0; h < HL_; h++) {
                float av = at_s[h];
                u32 u = lf_s[h * 224 + tid];
                union { u32 i; float f; } lo, hi;
                lo.i = u << 16; hi.i = u & 0xffff0000u;
                a0 = fmaf(av, lo.f, a0);
                a1 = fmaf(av, hi.f, a1);
            }
            float2* orow = (float2*)(out + (size_t)gid * NEWS_DIM);
            orow[tid] = make_float2(a0, a1);
        }
        __syncthreads();
    }
}

// ---------------- K5: nf = [news_vec | zeros] f32 (pos_emb[0]==0), written LAST
__global__ __launch_bounds__(256) void nf_k(
    const float* __restrict__ newsv, float* __restrict__ nf)
{
    u32 i = blockIdx.x * 256u + threadIdx.x;   // float2 id; 4096*224 total, exact grid
    u32 r = i / 224u, c = i - r * 224u;        // d = 2c
    float2 v = make_float2(0.f, 0.f);
    if (c < 192u) v = *(const float2*)(newsv + (size_t)r * IN_DIM + c * 2u);
    *(float2*)(nf + (size_t)r * NEWS_DIM + c * 2u) = v;
}

extern "C" void kernel_launch(void* const* d_in, const int* in_sizes, int n_in,
                              void* d_out, int out_size, void* d_ws, size_t ws_size,
                              hipStream_t stream) {
    const float* logv  = (const float*)d_in[0];  // (64,50,384) f32
    const int*   lmask = (const int*)d_in[1];    // (64,50) i32
    const float* newsv = (const float*)d_in[2];  // (64,64,384) f32
    const float* pos   = (const float*)d_in[3];  // (100,64) f32; row 0 == 0
    const float* W1    = (const float*)d_in[4];  // (256,896) f32
    const float* b1    = (const float*)d_in[5];  // (256,) f32
    const float* w2    = (const float*)d_in[6];  // (1,256) f32
    // b2 unused (softmax-invariant shift)

    // OUTPUT IS F32 (round-4 error 4.72 == packed-bf16 read back as f32).
    // d_out = 3,670,016 f32 (14.68 MB). Scratch inside d_out, d_ws untouched:
    //   R0 = out[0 .. 1,835,008)          : user_log_vecs (written by K4)
    //   R1 = out[1,835,008 .. 3,670,016)  : nf (written LAST by K5)
    // pn  f32 @ R0[0, 1,048,576)            (dead before K4 writes R0)
    // plT f32 @ R1[+0, 819,200)             (dead before K5)
    // attn f32 @ R1[+819,200, +1,081,344)   (dead before K5)
    float* out  = (float*)d_out;
    float* pn   = out;
    float* plT  = out + 1835008;
    float* attn = out + 2654208;
    float* nf   = out + 1835008;

    gemm_pn <<<dim3(64, 4), 64, 0, stream>>>(newsv, W1, b1, pn);
    gemm_plT<<<dim3(50, 4), 64, 0, stream>>>(logv, pos, W1, plT);
    attn_k  <<<B_ * NN_ / 4, 256, 0, stream>>>(pn, plT, w2, lmask, attn);
    out_k   <<<dim3(4, B_), 256, 0, stream>>>(logv, pos, attn, out);
    nf_k    <<<B_ * NN_ * 224 / 256, 256, 0, stream>>>(newsv, nf);
}

// Round 6
// 159.903 us; speedup vs baseline: 1.5074x; 1.5074x over previous
//
#include <hip/hip_runtime.h>
#include <math.h>

typedef unsigned short u16;
typedef unsigned int   u32;

#define B_       64
#define NN_      64
#define HL_      50
#define IN_DIM   384
#define POS_DIM  64
#define ATT_DIM  256
#define NEWS_DIM 448   // IN_DIM + POS_DIM

typedef __attribute__((ext_vector_type(8))) short short8;   // bf16x8 MFMA frag
typedef __attribute__((ext_vector_type(4))) float f32x4;    // MFMA acc

#if __has_builtin(__builtin_amdgcn_exp2f)
#define EXP2F(x) __builtin_amdgcn_exp2f(x)
#else
#define EXP2F(x) exp2f(x)
#endif
#if __has_builtin(__builtin_amdgcn_rcpf)
#define RCPF(x) __builtin_amdgcn_rcpf(x)
#else
#define RCPF(x) (1.0f/(x))
#endif

__device__ __forceinline__ u16 f2bf(float f) {
    union { float f; u32 i; } v; v.f = f;
    u32 r = v.i + 0x7fffu + ((v.i >> 16) & 1u);   // RNE
    return (u16)(r >> 16);
}
// pack 8 consecutive f32 -> bf16x8 fragment
__device__ __forceinline__ short8 pack8(const float* p) {
    union { short8 v; u16 e[8]; } r;
#pragma unroll
    for (int j = 0; j < 8; j++) r.e[j] = f2bf(p[j]);
    return r.v;
}
// tanh(x) = 1 - 2/(1+2^(x*2*log2e)); v_exp+v_rcp saturate correctly at +-inf.
__device__ __forceinline__ float fast_tanh(float x) {
    float e = EXP2F(x * 2.88539008f);
    return 1.0f - 2.0f * RCPF(1.0f + e);
}

// ---------------- K1: pn = newsv(4096x384) . W1[:, :384]^T + b1 -> f32 scratch
// (pos_emb[0]==0 exactly, so nf tail contributes nothing: K=384.)
__global__ __launch_bounds__(64) void gemm_pn(
    const float* __restrict__ A, const float* __restrict__ W,
    const float* __restrict__ bias, float* __restrict__ pn)
{
    int lane = threadIdx.x;
    int m = lane & 15, q = lane >> 4;
    int r0 = blockIdx.x * 64, c0 = blockIdx.y * 64;
    f32x4 acc[4][4];
#pragma unroll
    for (int a = 0; a < 4; a++)
#pragma unroll
        for (int b = 0; b < 4; b++) acc[a][b] = (f32x4){0.f, 0.f, 0.f, 0.f};

    const float* Ap = A + (size_t)(r0 + m) * IN_DIM + q * 8;
    const float* Wp = W + (size_t)(c0 + m) * (2 * NEWS_DIM) + q * 8;

    for (int k = 0; k < IN_DIM; k += 32) {
        short8 af[4], wf[4];
#pragma unroll
        for (int rt = 0; rt < 4; rt++) af[rt] = pack8(Ap + rt * 16 * IN_DIM + k);
#pragma unroll
        for (int ct = 0; ct < 4; ct++) wf[ct] = pack8(Wp + ct * 16 * (2 * NEWS_DIM) + k);
#pragma unroll
        for (int rt = 0; rt < 4; rt++)
#pragma unroll
            for (int ct = 0; ct < 4; ct++)
                acc[rt][ct] = __builtin_amdgcn_mfma_f32_16x16x32_bf16(
                    af[rt], wf[ct], acc[rt][ct], 0, 0, 0);
    }
    // C/D layout: col = lane&15, row = (lane>>4)*4 + i  [m89]
#pragma unroll
    for (int rt = 0; rt < 4; rt++)
#pragma unroll
        for (int ct = 0; ct < 4; ct++)
#pragma unroll
            for (int i = 0; i < 4; i++) {
                int gr = r0 + rt * 16 + q * 4 + i;
                int gc = c0 + ct * 16 + m;
                pn[(size_t)gr * ATT_DIM + gc] = acc[rt][ct][i] + bias[gc];
            }
}

// ---------------- K2: plT = (virtual lf)(3200x448) . W1[:, 448:]^T -> f32, transposed
// lf row r=(b*50+h): d<384 -> logv[r*384+d]; d>=384 -> pos[(1+h)*64 + d-384].
__global__ __launch_bounds__(64) void gemm_plT(
    const float* __restrict__ logv, const float* __restrict__ pos,
    const float* __restrict__ W, float* __restrict__ plT)
{
    int lane = threadIdx.x;
    int m = lane & 15, q = lane >> 4;
    int r0 = blockIdx.x * 64, c0 = blockIdx.y * 64;
    f32x4 acc[4][4];
#pragma unroll
    for (int a = 0; a < 4; a++)
#pragma unroll
        for (int b = 0; b < 4; b++) acc[a][b] = (f32x4){0.f, 0.f, 0.f, 0.f};

    const float* Lp[4]; const float* Pp[4];
#pragma unroll
    for (int rt = 0; rt < 4; rt++) {
        int r = r0 + m + rt * 16;
        int h = r % HL_;
        Lp[rt] = logv + (size_t)r * IN_DIM + q * 8;
        Pp[rt] = pos + (size_t)(1 + h) * POS_DIM + q * 8;
    }
    const float* Wp = W + (size_t)(c0 + m) * (2 * NEWS_DIM) + NEWS_DIM + q * 8;

    for (int k = 0; k < IN_DIM; k += 32) {       // logv part
        short8 af[4], wf[4];
#pragma unroll
        for (int rt = 0; rt < 4; rt++) af[rt] = pack8(Lp[rt] + k);
#pragma unroll
        for (int ct = 0; ct < 4; ct++) wf[ct] = pack8(Wp + ct * 16 * (2 * NEWS_DIM) + k);
#pragma unroll
        for (int rt = 0; rt < 4; rt++)
#pragma unroll
            for (int ct = 0; ct < 4; ct++)
                acc[rt][ct] = __builtin_amdgcn_mfma_f32_16x16x32_bf16(
                    af[rt], wf[ct], acc[rt][ct], 0, 0, 0);
    }
#pragma unroll
    for (int k = IN_DIM; k < NEWS_DIM; k += 32) { // pos part (k=384,416)
        short8 af[4], wf[4];
#pragma unroll
        for (int rt = 0; rt < 4; rt++) af[rt] = pack8(Pp[rt] + (k - IN_DIM));
#pragma unroll
        for (int ct = 0; ct < 4; ct++) wf[ct] = pack8(Wp + ct * 16 * (2 * NEWS_DIM) + k);
#pragma unroll
        for (int rt = 0; rt < 4; rt++)
#pragma unroll
            for (int ct = 0; ct < 4; ct++)
                acc[rt][ct] = __builtin_amdgcn_mfma_f32_16x16x32_bf16(
                    af[rt], wf[ct], acc[rt][ct], 0, 0, 0);
    }
#pragma unroll
    for (int rt = 0; rt < 4; rt++)
#pragma unroll
        for (int ct = 0; ct < 4; ct++)
#pragma unroll
            for (int i = 0; i < 4; i++) {
                int gr = r0 + rt * 16 + q * 4 + i;      // row in [0,3200)
                int gc = c0 + ct * 16 + m;              // a in [0,256)
                int bb = gr / HL_, hh = gr - bb * HL_;
                plT[(size_t)(bb * ATT_DIM + gc) * HL_ + hh] = acc[rt][ct][i];
            }
}

// ---------------- K3: logits -> masked softmax. One wave per (b,n), lane = h.
// fast_tanh (v_exp+v_rcp) replaces libm tanhf: round-5 profile showed attn_k
// at 105us, MfmaUtil=0, HBM 1.9%, VALUBusy 47% -- pure transcendental serialization.
__global__ __launch_bounds__(256) void attn_k(
    const float* __restrict__ pn, const float* __restrict__ plT,
    const float* __restrict__ w2, const int* __restrict__ lmask,
    float* __restrict__ attn)
{
    int lane = threadIdx.x & 63;
    int wid = (int)(threadIdx.x >> 6);
    int gid = blockIdx.x * 4 + wid;            // b*64 + n
    int b = gid >> 6;
    int hl = (lane < HL_) ? lane : (HL_ - 1);  // clamp: keep reads in-bounds
    const float* pr = pn + (size_t)gid * ATT_DIM;        // b1 folded in
    const float* pl = plT + (size_t)b * ATT_DIM * HL_ + hl;
    float acc0 = 0.f, acc1 = 0.f;
#pragma unroll 4
    for (int a = 0; a < ATT_DIM; a += 2) {
        float x0 = pr[a]     + pl[a * HL_];
        float x1 = pr[a + 1] + pl[(a + 1) * HL_];
        acc0 = __builtin_fmaf(fast_tanh(x0), w2[a], acc0);
        acc1 = __builtin_fmaf(fast_tanh(x1), w2[a + 1], acc1);
    }
    float acc = acc0 + acc1;
    int mv = (lane < HL_) ? lmask[b * HL_ + lane] : 0;
    float logit = mv ? acc : -1e9f;            // b2 dropped: softmax-invariant
    float mx = logit;
#pragma unroll
    for (int o = 32; o > 0; o >>= 1) mx = fmaxf(mx, __shfl_xor(mx, o));
    float e = EXP2F((logit - mx) * 1.44269504f);   // masked lanes -> 0
    float s = e;
#pragma unroll
    for (int o = 32; o > 0; o >>= 1) s += __shfl_xor(s, o);
    attn[(size_t)gid * 64 + lane] = e * RCPF(s);
}

// ---------------- K4: out[b,n,:] = sum_h attn[b,n,h] * lf[b,h,:]  (f32 stores)
// Virtual lf staged in LDS as packed bf16 pairs. Block = (b, 16 n's).
__global__ __launch_bounds__(256) void out_k(
    const float* __restrict__ logv, const float* __restrict__ pos,
    const float* __restrict__ attn, float* __restrict__ out)
{
    __shared__ __align__(16) u32 lf_s[HL_ * NEWS_DIM / 2];  // 224 u32/row, 44800 B
    __shared__ float at_s[64];
    int tid = threadIdx.x;
    int b = blockIdx.y, n0 = blockIdx.x * 16;

    const float4* Ls = (const float4*)(logv + (size_t)b * HL_ * IN_DIM);
    for (int i = tid; i < HL_ * IN_DIM / 4; i += 256) {    // 4800 float4 chunks
        int h = i / (IN_DIM / 4), c = i - h * (IN_DIM / 4);
        float4 v = Ls[i];
        u32* dst = lf_s + h * (NEWS_DIM / 2) + c * 2;
        dst[0] = (u32)f2bf(v.x) | ((u32)f2bf(v.y) << 16);
        dst[1] = (u32)f2bf(v.z) | ((u32)f2bf(v.w) << 16);
    }
    for (int i = tid; i < HL_ * POS_DIM / 4; i += 256) {   // 800 float4 chunks
        int h = i / (POS_DIM / 4), c = i - h * (POS_DIM / 4);
        float4 v = *(const float4*)(pos + (size_t)(1 + h) * POS_DIM + c * 4);
        u32* dst = lf_s + h * (NEWS_DIM / 2) + IN_DIM / 2 + c * 2;
        dst[0] = (u32)f2bf(v.x) | ((u32)f2bf(v.y) << 16);
        dst[1] = (u32)f2bf(v.z) | ((u32)f2bf(v.w) << 16);
    }
    __syncthreads();

    for (int ni = 0; ni < 16; ni++) {
        int gid = b * 64 + (n0 + ni);
        if (tid < 64) at_s[tid] = attn[(size_t)gid * 64 + tid];
        __syncthreads();
        if (tid < 224) {                                   // d = 2*tid, 2*tid+1
            float a0 = 0.f, a1 = 0.f;
#pragma unroll 5
            for (int h = 0; h < HL_; h++) {
                float av = at_s[h];
                u32 u = lf_s[h * 224 + tid];
                union { u32 i; float f; } lo, hi;
                lo.i = u << 16; hi.i = u & 0xffff0000u;
                a0 = fmaf(av, lo.f, a0);
                a1 = fmaf(av, hi.f, a1);
            }
            float2* orow = (float2*)(out + (size_t)gid * NEWS_DIM);
            orow[tid] = make_float2(a0, a1);
        }
        __syncthreads();
    }
}

// ---------------- K5: nf = [news_vec | zeros] f32 (pos_emb[0]==0), written LAST
__global__ __launch_bounds__(256) void nf_k(
    const float* __restrict__ newsv, float* __restrict__ nf)
{
    u32 i = blockIdx.x * 256u + threadIdx.x;   // float2 id; 4096*224 total, exact grid
    u32 r = i / 224u, c = i - r * 224u;        // d = 2c
    float2 v = make_float2(0.f, 0.f);
    if (c < 192u) v = *(const float2*)(newsv + (size_t)r * IN_DIM + c * 2u);
    *(float2*)(nf + (size_t)r * NEWS_DIM + c * 2u) = v;
}

extern "C" void kernel_launch(void* const* d_in, const int* in_sizes, int n_in,
                              void* d_out, int out_size, void* d_ws, size_t ws_size,
                              hipStream_t stream) {
    const float* logv  = (const float*)d_in[0];  // (64,50,384) f32
    const int*   lmask = (const int*)d_in[1];    // (64,50) i32
    const float* newsv = (const float*)d_in[2];  // (64,64,384) f32
    const float* pos   = (const float*)d_in[3];  // (100,64) f32; row 0 == 0
    const float* W1    = (const float*)d_in[4];  // (256,896) f32
    const float* b1    = (const float*)d_in[5];  // (256,) f32
    const float* w2    = (const float*)d_in[6];  // (1,256) f32
    // b2 unused (softmax-invariant shift)

    // OUTPUT IS F32. d_out = 3,670,016 f32 (14.68 MB). Scratch inside d_out:
    //   R0 = out[0 .. 1,835,008)          : user_log_vecs (written by K4)
    //   R1 = out[1,835,008 .. 3,670,016)  : nf (written LAST by K5)
    // pn  f32 @ R0[0, 1,048,576)            (dead before K4 writes R0)
    // plT f32 @ R1[+0, 819,200)             (dead before K5)
    // attn f32 @ R1[+819,200, +1,081,344)   (dead before K5)
    float* out  = (float*)d_out;
    float* pn   = out;
    float* plT  = out + 1835008;
    float* attn = out + 2654208;
    float* nf   = out + 1835008;

    gemm_pn <<<dim3(64, 4), 64, 0, stream>>>(newsv, W1, b1, pn);
    gemm_plT<<<dim3(50, 4), 64, 0, stream>>>(logv, pos, W1, plT);
    attn_k  <<<B_ * NN_ / 4, 256, 0, stream>>>(pn, plT, w2, lmask, attn);
    out_k   <<<dim3(4, B_), 256, 0, stream>>>(logv, pos, attn, out);
    nf_k    <<<B_ * NN_ * 224 / 256, 256, 0, stream>>>(newsv, nf);
}

// Round 7
// 146.875 us; speedup vs baseline: 1.6411x; 1.0887x over previous
//
#include <hip/hip_runtime.h>
#include <math.h>

typedef unsigned short u16;
typedef unsigned int   u32;

#define B_       64
#define NN_      64
#define HL_      50
#define IN_DIM   384
#define POS_DIM  64
#define ATT_DIM  256
#define NEWS_DIM 448   // IN_DIM + POS_DIM

typedef __attribute__((ext_vector_type(8))) short short8;   // bf16x8 MFMA frag
typedef __attribute__((ext_vector_type(4))) float f32x4;    // MFMA acc

#if __has_builtin(__builtin_amdgcn_exp2f)
#define EXP2F(x) __builtin_amdgcn_exp2f(x)
#else
#define EXP2F(x) exp2f(x)
#endif
#if __has_builtin(__builtin_amdgcn_rcpf)
#define RCPF(x) __builtin_amdgcn_rcpf(x)
#else
#define RCPF(x) (1.0f/(x))
#endif

__device__ __forceinline__ u16 f2bf(float f) {
    union { float f; u32 i; } v; v.f = f;
    u32 r = v.i + 0x7fffu + ((v.i >> 16) & 1u);   // RNE
    return (u16)(r >> 16);
}
__device__ __forceinline__ uint2 pack4(float4 v) {
    return make_uint2((u32)f2bf(v.x) | ((u32)f2bf(v.y) << 16),
                      (u32)f2bf(v.z) | ((u32)f2bf(v.w) << 16));
}
// tanh(x) = 1 - 2/(1+2^(x*2*log2e)); v_exp+v_rcp saturate correctly at +-inf.
__device__ __forceinline__ float fast_tanh(float x) {
    float e = EXP2F(x * 2.88539008f);
    return 1.0f - 2.0f * RCPF(1.0f + e);
}

// prep segments, in 4-f32 chunks
#define C_W   57344u     // W1 (256x896)
#define C_NV  393216u    // newsv (4096x384) -> nv_bf AND nf f32 head
#define C_LG  307200u    // logv (3200x384) -> lf_bf head
#define C_PS  51200u     // pos rows 1..50 -> lf_bf tail
#define C_NZ  65536u     // nf f32 zero tail (4096x64)
#define C_TOT (C_W + C_NV + C_LG + C_PS + C_NZ)   // 874,496

// ---------------- K0: convert W1/newsv/lf to bf16 in ws; emit nf (f32) to d_out.
__global__ __launch_bounds__(256) void prep_k(
    const float* __restrict__ W1, const float* __restrict__ newsv,
    const float* __restrict__ logv, const float* __restrict__ pos,
    u16* __restrict__ Wbf, u16* __restrict__ nv_bf, u16* __restrict__ lf_bf,
    float* __restrict__ nf)
{
    u32 i = blockIdx.x * 256u + threadIdx.x;
    if (i < C_W) {                                   // W1 -> Wbf
        float4 v = *(const float4*)(W1 + (size_t)i * 4u);
        *(uint2*)(Wbf + (size_t)i * 4u) = pack4(v);
        return;
    }
    i -= C_W;
    if (i < C_NV) {                                  // newsv -> nv_bf + nf head
        float4 v = *(const float4*)(newsv + (size_t)i * 4u);
        *(uint2*)(nv_bf + (size_t)i * 4u) = pack4(v);
        u32 e = i * 4u, r = e / IN_DIM, d = e - r * IN_DIM;
        *(float4*)(nf + (size_t)r * NEWS_DIM + d) = v;
        return;
    }
    i -= C_NV;
    if (i < C_LG) {                                  // logv -> lf_bf head
        float4 v = *(const float4*)(logv + (size_t)i * 4u);
        u32 e = i * 4u, r = e / IN_DIM, d = e - r * IN_DIM;
        *(uint2*)(lf_bf + (size_t)r * NEWS_DIM + d) = pack4(v);
        return;
    }
    i -= C_LG;
    if (i < C_PS) {                                  // pos rows 1..50 -> lf_bf tail
        u32 e = i * 4u, r = e / POS_DIM, d = e - r * POS_DIM;
        u32 h = r % HL_;
        float4 v = *(const float4*)(pos + (size_t)(1u + h) * POS_DIM + d);
        *(uint2*)(lf_bf + (size_t)r * NEWS_DIM + IN_DIM + d) = pack4(v);
        return;
    }
    i -= C_PS;
    if (i < C_NZ) {                                  // nf zero tail
        u32 e = i * 4u, r = e / POS_DIM, d = e - r * POS_DIM;
        *(float4*)(nf + (size_t)r * NEWS_DIM + IN_DIM + d) = make_float4(0.f, 0.f, 0.f, 0.f);
    }
}

// ---------------- K1: fused NT GEMMs, pure bf16 loads (no conversion VALU).
// bid < 256: pn[4096x256] = nv_bf . Wbf[:, :384]^T + b1
// bid >= 256: plT[(b*256+a)*50+h] = lf_bf . Wbf[:, 448:]^T  (transposed store)
__global__ __launch_bounds__(64) void gemm_k(
    const u16* __restrict__ nv_bf, const u16* __restrict__ lf_bf,
    const u16* __restrict__ Wbf, const float* __restrict__ b1,
    float* __restrict__ pn, float* __restrict__ plT)
{
    int bid = blockIdx.x;
    int lane = threadIdx.x;
    int m = lane & 15, q = lane >> 4;
    bool is_pn = bid < 256;
    int r0, c0, lda, koff, klen;
    const u16* A;
    if (is_pn) { r0 = (bid & 63) * 64;       c0 = (bid >> 6) * 64; A = nv_bf; lda = IN_DIM;   koff = 0;        klen = IN_DIM; }
    else { int b2 = bid - 256; r0 = (b2 % 50) * 64; c0 = (b2 / 50) * 64; A = lf_bf; lda = NEWS_DIM; koff = NEWS_DIM; klen = NEWS_DIM; }

    f32x4 acc[4][4];
#pragma unroll
    for (int a = 0; a < 4; a++)
#pragma unroll
        for (int b = 0; b < 4; b++) acc[a][b] = (f32x4){0.f, 0.f, 0.f, 0.f};

    const u16* Ap = A + (size_t)(r0 + m) * lda + q * 8;
    const u16* Wp = Wbf + (size_t)(c0 + m) * (2 * NEWS_DIM) + koff + q * 8;

    for (int k = 0; k < klen; k += 32) {
        short8 af[4], wf[4];
#pragma unroll
        for (int rt = 0; rt < 4; rt++) af[rt] = *(const short8*)(Ap + rt * 16 * lda + k);
#pragma unroll
        for (int ct = 0; ct < 4; ct++) wf[ct] = *(const short8*)(Wp + ct * 16 * (2 * NEWS_DIM) + k);
#pragma unroll
        for (int rt = 0; rt < 4; rt++)
#pragma unroll
            for (int ct = 0; ct < 4; ct++)
                acc[rt][ct] = __builtin_amdgcn_mfma_f32_16x16x32_bf16(
                    af[rt], wf[ct], acc[rt][ct], 0, 0, 0);
    }
    // C/D layout: col = lane&15, row = (lane>>4)*4 + i  [m89]
#pragma unroll
    for (int rt = 0; rt < 4; rt++)
#pragma unroll
        for (int ct = 0; ct < 4; ct++)
#pragma unroll
            for (int i = 0; i < 4; i++) {
                int gr = r0 + rt * 16 + q * 4 + i;
                int gc = c0 + ct * 16 + m;
                float v = acc[rt][ct][i];
                if (is_pn) {
                    pn[(size_t)gr * ATT_DIM + gc] = v + b1[gc];
                } else {
                    int bb = gr / HL_, hh = gr - bb * HL_;
                    plT[(size_t)(bb * ATT_DIM + gc) * HL_ + hh] = v;
                }
            }
}

// ---------------- K2: logits -> masked softmax. One wave per (b,n), lane = h.
__global__ __launch_bounds__(256) void attn_k(
    const float* __restrict__ pn, const float* __restrict__ plT,
    const float* __restrict__ w2, const int* __restrict__ lmask,
    float* __restrict__ attn)
{
    int lane = threadIdx.x & 63;
    int wid = (int)(threadIdx.x >> 6);
    int gid = blockIdx.x * 4 + wid;            // b*64 + n
    int b = gid >> 6;
    int hl = (lane < HL_) ? lane : (HL_ - 1);  // clamp: keep reads in-bounds
    const float* pr = pn + (size_t)gid * ATT_DIM;        // b1 folded in
    const float* pl = plT + (size_t)b * ATT_DIM * HL_ + hl;
    float acc0 = 0.f, acc1 = 0.f, acc2 = 0.f, acc3 = 0.f;
#pragma unroll 2
    for (int a = 0; a < ATT_DIM; a += 4) {
        float4 p = *(const float4*)(pr + a);   // wave-uniform broadcast
        float4 w = *(const float4*)(w2 + a);
        acc0 = __builtin_fmaf(fast_tanh(p.x + pl[(a + 0) * HL_]), w.x, acc0);
        acc1 = __builtin_fmaf(fast_tanh(p.y + pl[(a + 1) * HL_]), w.y, acc1);
        acc2 = __builtin_fmaf(fast_tanh(p.z + pl[(a + 2) * HL_]), w.z, acc2);
        acc3 = __builtin_fmaf(fast_tanh(p.w + pl[(a + 3) * HL_]), w.w, acc3);
    }
    float acc = (acc0 + acc1) + (acc2 + acc3);
    int mv = (lane < HL_) ? lmask[b * HL_ + lane] : 0;
    float logit = mv ? acc : -1e9f;            // b2 dropped: softmax-invariant
    float mx = logit;
#pragma unroll
    for (int o = 32; o > 0; o >>= 1) mx = fmaxf(mx, __shfl_xor(mx, o));
    float e = EXP2F((logit - mx) * 1.44269504f);   // masked lanes -> 0
    float s = e;
#pragma unroll
    for (int o = 32; o > 0; o >>= 1) s += __shfl_xor(s, o);
    attn[(size_t)gid * 64 + lane] = e * RCPF(s);
}

// ---------------- K3: out[b,n,:] = sum_h attn[b,n,h] * lf[b,h,:]  (f32 stores)
// lf already bf16 in ws: plain uint4 LDS staging. Block = (b, 16 n's).
__global__ __launch_bounds__(256) void out_k(
    const u16* __restrict__ lf_bf, const float* __restrict__ attn,
    float* __restrict__ out)
{
    __shared__ __align__(16) u32 lf_s[HL_ * NEWS_DIM / 2];  // 224 u32/row, 44800 B
    __shared__ float at_s[64];
    int tid = threadIdx.x;
    int b = blockIdx.y, n0 = blockIdx.x * 16;

    const uint4* src = (const uint4*)(lf_bf + (size_t)b * HL_ * NEWS_DIM);
    uint4* dst = (uint4*)lf_s;
    for (int i = tid; i < HL_ * NEWS_DIM / 8; i += 256) dst[i] = src[i];  // 2800
    __syncthreads();

    for (int ni = 0; ni < 16; ni++) {
        int gid = b * 64 + (n0 + ni);
        if (tid < 64) at_s[tid] = attn[(size_t)gid * 64 + tid];
        __syncthreads();
        if (tid < 224) {                                   // d = 2*tid, 2*tid+1
            float a0 = 0.f, a1 = 0.f;
#pragma unroll 5
            for (int h = 0; h < HL_; h++) {
                float av = at_s[h];
                u32 u = lf_s[h * 224 + tid];
                union { u32 i; float f; } lo, hi;
                lo.i = u << 16; hi.i = u & 0xffff0000u;
                a0 = fmaf(av, lo.f, a0);
                a1 = fmaf(av, hi.f, a1);
            }
            float2* orow = (float2*)(out + (size_t)gid * NEWS_DIM);
            orow[tid] = make_float2(a0, a1);
        }
        __syncthreads();
    }
}

extern "C" void kernel_launch(void* const* d_in, const int* in_sizes, int n_in,
                              void* d_out, int out_size, void* d_ws, size_t ws_size,
                              hipStream_t stream) {
    const float* logv  = (const float*)d_in[0];  // (64,50,384) f32
    const int*   lmask = (const int*)d_in[1];    // (64,50) i32
    const float* newsv = (const float*)d_in[2];  // (64,64,384) f32
    const float* pos   = (const float*)d_in[3];  // (100,64) f32; row 0 == 0
    const float* W1    = (const float*)d_in[4];  // (256,896) f32
    const float* b1    = (const float*)d_in[5];  // (256,) f32
    const float* w2    = (const float*)d_in[6];  // (1,256) f32
    // b2 unused (softmax-invariant shift)

    float* out = (float*)d_out;                  // [user_log | nf], f32
    float* nf  = out + (size_t)B_ * NN_ * NEWS_DIM;

    // d_ws is ~256 MiB (round-6 profile: 268 MB poison fill). Byte offsets, 16B aligned:
    char* ws = (char*)d_ws;
    u16*   lf_bf = (u16*)(ws + 0);               // 3200x448 bf16  (2,867,200 B)
    u16*   Wbf   = (u16*)(ws + 2867200);         // 256x896 bf16   (458,752 B)
    u16*   nv_bf = (u16*)(ws + 3325952);         // 4096x384 bf16  (3,145,728 B)
    float* pn    = (float*)(ws + 6471680);       // 4096x256 f32   (4,194,304 B)
    float* plT   = (float*)(ws + 10665984);      // 64x256x50 f32  (3,276,800 B)
    float* attn  = (float*)(ws + 13942784);      // 4096x64 f32    (1,048,576 B)

    prep_k<<<(C_TOT + 255) / 256, 256, 0, stream>>>(W1, newsv, logv, pos,
                                                    Wbf, nv_bf, lf_bf, nf);
    gemm_k<<<456, 64, 0, stream>>>(nv_bf, lf_bf, Wbf, b1, pn, plT);
    attn_k<<<B_ * NN_ / 4, 256, 0, stream>>>(pn, plT, w2, lmask, attn);
    out_k <<<dim3(4, B_), 256, 0, stream>>>(lf_bf, attn, out);
}

// Round 8
// 137.441 us; speedup vs baseline: 1.7538x; 1.0686x over previous
//
#include <hip/hip_runtime.h>
#include <math.h>

typedef unsigned short u16;
typedef unsigned int   u32;

#define B_       64
#define NN_      64
#define HL_      50
#define IN_DIM   384
#define POS_DIM  64
#define ATT_DIM  256
#define NEWS_DIM 448   // IN_DIM + POS_DIM

typedef __attribute__((ext_vector_type(8))) short short8;   // bf16x8 MFMA frag
typedef __attribute__((ext_vector_type(4))) float f32x4;    // MFMA acc

#if __has_builtin(__builtin_amdgcn_exp2f)
#define EXP2F(x) __builtin_amdgcn_exp2f(x)
#else
#define EXP2F(x) exp2f(x)
#endif
#if __has_builtin(__builtin_amdgcn_rcpf)
#define RCPF(x) __builtin_amdgcn_rcpf(x)
#else
#define RCPF(x) (1.0f/(x))
#endif

__device__ __forceinline__ u16 f2bf(float f) {
    union { float f; u32 i; } v; v.f = f;
    u32 r = v.i + 0x7fffu + ((v.i >> 16) & 1u);   // RNE
    return (u16)(r >> 16);
}
__device__ __forceinline__ uint2 pack4(float4 v) {
    return make_uint2((u32)f2bf(v.x) | ((u32)f2bf(v.y) << 16),
                      (u32)f2bf(v.z) | ((u32)f2bf(v.w) << 16));
}
// tanh(x) = 1 - 2/(1+2^(x*2*log2e)); v_exp+v_rcp saturate correctly at +-inf.
__device__ __forceinline__ float fast_tanh(float x) {
    float e = EXP2F(x * 2.88539008f);
    return 1.0f - 2.0f * RCPF(1.0f + e);
}

// prep segments, in 4-f32 chunks (except C_LTZ: one thread per (b,d))
#define C_W   57344u     // W1 (256x896) -> Wbf
#define C_NV  393216u    // newsv (4096x384) -> nv_bf AND nf f32 head
#define C_LG  307200u    // logv (3200x384) -> lf_bf head + lfT_bf scatter
#define C_PS  51200u     // pos rows 1..50 -> lf_bf tail + lfT_bf scatter
#define C_NZ  65536u     // nf f32 zero tail (4096x64)
#define C_LTZ 28672u     // lfT_bf h in [50,64) zero pad, one thread per (b,d)
#define C_TOT (C_W + C_NV + C_LG + C_PS + C_NZ + C_LTZ)   // 903,168 = 3528*256

// ---------------- K0: bf16-convert W1/newsv/lf (+transposed lfT) into ws; nf->d_out.
__global__ __launch_bounds__(256) void prep_k(
    const float* __restrict__ W1, const float* __restrict__ newsv,
    const float* __restrict__ logv, const float* __restrict__ pos,
    u16* __restrict__ Wbf, u16* __restrict__ nv_bf, u16* __restrict__ lf_bf,
    u16* __restrict__ lfT_bf, float* __restrict__ nf)
{
    u32 i = blockIdx.x * 256u + threadIdx.x;
    if (i < C_W) {                                   // W1 -> Wbf
        float4 v = *(const float4*)(W1 + (size_t)i * 4u);
        *(uint2*)(Wbf + (size_t)i * 4u) = pack4(v);
        return;
    }
    i -= C_W;
    if (i < C_NV) {                                  // newsv -> nv_bf + nf head
        float4 v = *(const float4*)(newsv + (size_t)i * 4u);
        *(uint2*)(nv_bf + (size_t)i * 4u) = pack4(v);
        u32 e = i * 4u, r = e / IN_DIM, d = e - r * IN_DIM;
        *(float4*)(nf + (size_t)r * NEWS_DIM + d) = v;
        return;
    }
    i -= C_NV;
    if (i < C_LG) {                                  // logv -> lf_bf head + lfT
        float4 v = *(const float4*)(logv + (size_t)i * 4u);
        u32 e = i * 4u, r = e / IN_DIM, d = e - r * IN_DIM;
        *(uint2*)(lf_bf + (size_t)r * NEWS_DIM + d) = pack4(v);
        u32 b = r / HL_, h = r - b * HL_;
        u16* t = lfT_bf + ((size_t)b * NEWS_DIM + d) * 64u + h;
        t[0]   = f2bf(v.x); t[64]  = f2bf(v.y);
        t[128] = f2bf(v.z); t[192] = f2bf(v.w);
        return;
    }
    i -= C_LG;
    if (i < C_PS) {                                  // pos rows 1..50 -> lf tail + lfT
        u32 e = i * 4u, r = e / POS_DIM, d = e - r * POS_DIM;
        u32 b = r / HL_, h = r - b * HL_;
        float4 v = *(const float4*)(pos + (size_t)(1u + h) * POS_DIM + d);
        *(uint2*)(lf_bf + (size_t)r * NEWS_DIM + IN_DIM + d) = pack4(v);
        u16* t = lfT_bf + ((size_t)b * NEWS_DIM + IN_DIM + d) * 64u + h;
        t[0]   = f2bf(v.x); t[64]  = f2bf(v.y);
        t[128] = f2bf(v.z); t[192] = f2bf(v.w);
        return;
    }
    i -= C_PS;
    if (i < C_NZ) {                                  // nf zero tail
        u32 e = i * 4u, r = e / POS_DIM, d = e - r * POS_DIM;
        *(float4*)(nf + (size_t)r * NEWS_DIM + IN_DIM + d) = make_float4(0.f, 0.f, 0.f, 0.f);
        return;
    }
    i -= C_NZ;
    if (i < C_LTZ) {                                 // lfT h-pad zeros: 7 u32 per (b,d)
        u32* t = (u32*)lfT_bf + (size_t)i * 32u + 25u;   // h=50..63 (u16) = 7 u32
#pragma unroll
        for (int j = 0; j < 7; j++) t[j] = 0u;
    }
}

// ---------------- K1: fused NT GEMMs, pure bf16 16B loads.
// bid < 256: pn[4096x256] = nv_bf . Wbf[:, :384]^T + b1
// bid >= 256: plT[(b*256+a)*50+h] = lf_bf . Wbf[:, 448:]^T  (transposed store)
__global__ __launch_bounds__(64) void gemm_k(
    const u16* __restrict__ nv_bf, const u16* __restrict__ lf_bf,
    const u16* __restrict__ Wbf, const float* __restrict__ b1,
    float* __restrict__ pn, float* __restrict__ plT)
{
    int bid = blockIdx.x;
    int lane = threadIdx.x;
    int m = lane & 15, q = lane >> 4;
    bool is_pn = bid < 256;
    int r0, c0, lda, koff, klen;
    const u16* A;
    if (is_pn) { r0 = (bid & 63) * 64;       c0 = (bid >> 6) * 64; A = nv_bf; lda = IN_DIM;   koff = 0;        klen = IN_DIM; }
    else { int b2 = bid - 256; r0 = (b2 % 50) * 64; c0 = (b2 / 50) * 64; A = lf_bf; lda = NEWS_DIM; koff = NEWS_DIM; klen = NEWS_DIM; }

    f32x4 acc[4][4];
#pragma unroll
    for (int a = 0; a < 4; a++)
#pragma unroll
        for (int b = 0; b < 4; b++) acc[a][b] = (f32x4){0.f, 0.f, 0.f, 0.f};

    const u16* Ap = A + (size_t)(r0 + m) * lda + q * 8;
    const u16* Wp = Wbf + (size_t)(c0 + m) * (2 * NEWS_DIM) + koff + q * 8;

    for (int k = 0; k < klen; k += 32) {
        short8 af[4], wf[4];
#pragma unroll
        for (int rt = 0; rt < 4; rt++) af[rt] = *(const short8*)(Ap + rt * 16 * lda + k);
#pragma unroll
        for (int ct = 0; ct < 4; ct++) wf[ct] = *(const short8*)(Wp + ct * 16 * (2 * NEWS_DIM) + k);
#pragma unroll
        for (int rt = 0; rt < 4; rt++)
#pragma unroll
            for (int ct = 0; ct < 4; ct++)
                acc[rt][ct] = __builtin_amdgcn_mfma_f32_16x16x32_bf16(
                    af[rt], wf[ct], acc[rt][ct], 0, 0, 0);
    }
    // C/D layout: col = lane&15, row = (lane>>4)*4 + i  [m89]
#pragma unroll
    for (int rt = 0; rt < 4; rt++)
#pragma unroll
        for (int ct = 0; ct < 4; ct++)
#pragma unroll
            for (int i = 0; i < 4; i++) {
                int gr = r0 + rt * 16 + q * 4 + i;
                int gc = c0 + ct * 16 + m;
                float v = acc[rt][ct][i];
                if (is_pn) {
                    pn[(size_t)gr * ATT_DIM + gc] = v + b1[gc];
                } else {
                    int bb = gr / HL_, hh = gr - bb * HL_;
                    plT[(size_t)(bb * ATT_DIM + gc) * HL_ + hh] = v;
                }
            }
}

// ---------------- K2: logits -> masked softmax -> attn (bf16, h padded to 64).
// One wave per (b, n-PAIR): halves redundant plT traffic (round-7 model: attn_k
// was L2-BW bound on pl re-reads, ~31us; trans-pipe floor is 5.3us).
__global__ __launch_bounds__(256) void attn_k(
    const float* __restrict__ pn, const float* __restrict__ plT,
    const float* __restrict__ w2, const int* __restrict__ lmask,
    u16* __restrict__ attn_bf)
{
    int lane = threadIdx.x & 63;
    int w = (int)(threadIdx.x >> 6);
    int g = blockIdx.x * 4 + w;                // wave id in [0,2048)
    int b = g >> 5;
    int n0 = (g & 31) * 2;                     // n-pair
    int hl = (lane < HL_) ? lane : (HL_ - 1);  // clamp reads
    const float* pr0 = pn + ((size_t)b * NN_ + n0) * ATT_DIM;
    const float* pr1 = pr0 + ATT_DIM;
    const float* pl = plT + (size_t)b * ATT_DIM * HL_ + hl;

    float a00 = 0.f, a01 = 0.f, a10 = 0.f, a11 = 0.f;
#pragma unroll 2
    for (int a = 0; a < ATT_DIM; a += 4) {
        float4 w4 = *(const float4*)(w2 + a);
        float4 p0 = *(const float4*)(pr0 + a);
        float4 p1 = *(const float4*)(pr1 + a);
        float l0 = pl[(a + 0) * HL_];
        float l1 = pl[(a + 1) * HL_];
        float l2 = pl[(a + 2) * HL_];
        float l3 = pl[(a + 3) * HL_];
        a00 = __builtin_fmaf(fast_tanh(p0.x + l0), w4.x, a00);
        a10 = __builtin_fmaf(fast_tanh(p1.x + l0), w4.x, a10);
        a01 = __builtin_fmaf(fast_tanh(p0.y + l1), w4.y, a01);
        a11 = __builtin_fmaf(fast_tanh(p1.y + l1), w4.y, a11);
        a00 = __builtin_fmaf(fast_tanh(p0.z + l2), w4.z, a00);
        a10 = __builtin_fmaf(fast_tanh(p1.z + l2), w4.z, a10);
        a01 = __builtin_fmaf(fast_tanh(p0.w + l3), w4.w, a01);
        a11 = __builtin_fmaf(fast_tanh(p1.w + l3), w4.w, a11);
    }
    float acc0 = a00 + a01, acc1 = a10 + a11;
    int mv = (lane < HL_) ? lmask[b * HL_ + lane] : 0;
    float lg0 = mv ? acc0 : -1e9f;             // b2 dropped: softmax-invariant
    float lg1 = mv ? acc1 : -1e9f;
    float mx0 = lg0, mx1 = lg1;
#pragma unroll
    for (int o = 32; o > 0; o >>= 1) {
        mx0 = fmaxf(mx0, __shfl_xor(mx0, o));
        mx1 = fmaxf(mx1, __shfl_xor(mx1, o));
    }
    float e0 = EXP2F((lg0 - mx0) * 1.44269504f);   // masked/pad lanes -> 0
    float e1 = EXP2F((lg1 - mx1) * 1.44269504f);
    float s0 = e0, s1 = e1;
#pragma unroll
    for (int o = 32; o > 0; o >>= 1) {
        s0 += __shfl_xor(s0, o);
        s1 += __shfl_xor(s1, o);
    }
    u16* ab = attn_bf + (size_t)b * (NN_ * 64) + (size_t)n0 * 64 + lane;
    ab[0]  = f2bf(e0 * RCPF(s0));
    ab[64] = f2bf(e1 * RCPF(s1));
}

// ---------------- K3: out[b,n,:] = attn[b] (64x64) x lf[b] (64x448) via MFMA.
// A = attn_bf rows n (k=h contig); B = lfT_bf[d][h] (k=h contig, col=d).
// Block = (b, d-quarter); wave = n-tile of 16; 7 d-tiles/wave; no LDS.
__global__ __launch_bounds__(256) void out_k(
    const u16* __restrict__ attn_bf, const u16* __restrict__ lfT_bf,
    float* __restrict__ out)
{
    int bid = blockIdx.x;              // 256
    int b = bid >> 2, quad = bid & 3;
    int w = (int)(threadIdx.x >> 6);   // n-tile
    int lane = threadIdx.x & 63;
    int m = lane & 15, q = lane >> 4;
    int n0 = w * 16;

    const u16* Ap = attn_bf + (size_t)b * (NN_ * 64) + (size_t)(n0 + m) * 64 + q * 8;
    short8 a0 = *(const short8*)(Ap);        // k = 0..31
    short8 a1 = *(const short8*)(Ap + 32);   // k = 32..63 (attn pad rows = 0)
    const u16* Bb = lfT_bf + (size_t)b * NEWS_DIM * 64;

#pragma unroll
    for (int dt = 0; dt < 7; dt++) {
        int d0 = quad * 112 + dt * 16;
        const u16* Bp = Bb + (size_t)(d0 + m) * 64 + q * 8;
        short8 b0 = *(const short8*)(Bp);
        short8 b1 = *(const short8*)(Bp + 32);
        f32x4 c = (f32x4){0.f, 0.f, 0.f, 0.f};
        c = __builtin_amdgcn_mfma_f32_16x16x32_bf16(a0, b0, c, 0, 0, 0);
        c = __builtin_amdgcn_mfma_f32_16x16x32_bf16(a1, b1, c, 0, 0, 0);
        // lane holds C[n = n0+q*4+i][d = d0+m]
#pragma unroll
        for (int i = 0; i < 4; i++)
            out[((size_t)b * NN_ + n0 + q * 4 + i) * NEWS_DIM + d0 + m] = c[i];
    }
}

extern "C" void kernel_launch(void* const* d_in, const int* in_sizes, int n_in,
                              void* d_out, int out_size, void* d_ws, size_t ws_size,
                              hipStream_t stream) {
    const float* logv  = (const float*)d_in[0];  // (64,50,384) f32
    const int*   lmask = (const int*)d_in[1];    // (64,50) i32
    const float* newsv = (const float*)d_in[2];  // (64,64,384) f32
    const float* pos   = (const float*)d_in[3];  // (100,64) f32; row 0 == 0
    const float* W1    = (const float*)d_in[4];  // (256,896) f32
    const float* b1    = (const float*)d_in[5];  // (256,) f32
    const float* w2    = (const float*)d_in[6];  // (1,256) f32
    // b2 unused (softmax-invariant shift)

    float* out = (float*)d_out;                  // [user_log | nf], f32
    float* nf  = out + (size_t)B_ * NN_ * NEWS_DIM;

    // d_ws ~256 MiB. Byte offsets, 16B aligned:
    char* ws = (char*)d_ws;
    u16*   lf_bf   = (u16*)(ws + 0);             // 3200x448 bf16  (2,867,200 B)
    u16*   Wbf     = (u16*)(ws + 2867200);       // 256x896 bf16   (458,752 B)
    u16*   nv_bf   = (u16*)(ws + 3325952);       // 4096x384 bf16  (3,145,728 B)
    float* pn      = (float*)(ws + 6471680);     // 4096x256 f32   (4,194,304 B)
    float* plT     = (float*)(ws + 10665984);    // 64x256x50 f32  (3,276,800 B)
    u16*   lfT_bf  = (u16*)(ws + 13942784);      // 64x448x64 bf16 (3,670,016 B)
    u16*   attn_bf = (u16*)(ws + 17612800);      // 64x64x64 bf16  (524,288 B)

    prep_k<<<C_TOT / 256, 256, 0, stream>>>(W1, newsv, logv, pos,
                                            Wbf, nv_bf, lf_bf, lfT_bf, nf);
    gemm_k<<<456, 64, 0, stream>>>(nv_bf, lf_bf, Wbf, b1, pn, plT);
    attn_k<<<512, 256, 0, stream>>>(pn, plT, w2, lmask, attn_bf);
    out_k <<<256, 256, 0, stream>>>(attn_bf, lfT_bf, out);
}

// Round 9
// 134.509 us; speedup vs baseline: 1.7920x; 1.0218x over previous
//
#include <hip/hip_runtime.h>
#include <math.h>

typedef unsigned short u16;
typedef unsigned int   u32;

#define B_       64
#define NN_      64
#define HL_      50
#define IN_DIM   384
#define POS_DIM  64
#define ATT_DIM  256
#define NEWS_DIM 448   // IN_DIM + POS_DIM

typedef __attribute__((ext_vector_type(8))) short short8;   // bf16x8 MFMA frag
typedef __attribute__((ext_vector_type(4))) float f32x4;    // MFMA acc

#if __has_builtin(__builtin_amdgcn_exp2f)
#define EXP2F(x) __builtin_amdgcn_exp2f(x)
#else
#define EXP2F(x) exp2f(x)
#endif
#if __has_builtin(__builtin_amdgcn_rcpf)
#define RCPF(x) __builtin_amdgcn_rcpf(x)
#else
#define RCPF(x) (1.0f/(x))
#endif

__device__ __forceinline__ u16 f2bf(float f) {
    union { float f; u32 i; } v; v.f = f;
    u32 r = v.i + 0x7fffu + ((v.i >> 16) & 1u);   // RNE
    return (u16)(r >> 16);
}
__device__ __forceinline__ float bf2f(u16 u) {
    union { u32 i; float f; } v; v.i = ((u32)u) << 16; return v.f;
}
__device__ __forceinline__ uint2 pack4(float4 v) {
    return make_uint2((u32)f2bf(v.x) | ((u32)f2bf(v.y) << 16),
                      (u32)f2bf(v.z) | ((u32)f2bf(v.w) << 16));
}
// tanh(x) = 1 - 2/(1+2^(x*2*log2e)); v_exp+v_rcp saturate correctly at +-inf.
__device__ __forceinline__ float fast_tanh(float x) {
    float e = EXP2F(x * 2.88539008f);
    return 1.0f - 2.0f * RCPF(1.0f + e);
}

// prep segments, in 4-f32 chunks
#define C_W   57344u     // W1 (256x896) -> Wbf
#define C_NV  393216u    // newsv (4096x384) -> nv_bf AND nf f32 head
#define C_LG  307200u    // logv (3200x384) -> lf_bf head
#define C_PS  51200u     // pos rows 1..50 -> lf_bf tail
#define C_NZ  65536u     // nf f32 zero tail (4096x64)
#define C_TOT (C_W + C_NV + C_LG + C_PS + C_NZ)   // 874,496 = 3416*256

// ---------------- K0: bf16-convert W1/newsv/lf into ws; nf (f32) -> d_out.
__global__ __launch_bounds__(256) void prep_k(
    const float* __restrict__ W1, const float* __restrict__ newsv,
    const float* __restrict__ logv, const float* __restrict__ pos,
    u16* __restrict__ Wbf, u16* __restrict__ nv_bf, u16* __restrict__ lf_bf,
    float* __restrict__ nf)
{
    u32 i = blockIdx.x * 256u + threadIdx.x;
    if (i < C_W) {                                   // W1 -> Wbf
        float4 v = *(const float4*)(W1 + (size_t)i * 4u);
        *(uint2*)(Wbf + (size_t)i * 4u) = pack4(v);
        return;
    }
    i -= C_W;
    if (i < C_NV) {                                  // newsv -> nv_bf + nf head
        float4 v = *(const float4*)(newsv + (size_t)i * 4u);
        *(uint2*)(nv_bf + (size_t)i * 4u) = pack4(v);
        u32 e = i * 4u, r = e / IN_DIM, d = e - r * IN_DIM;
        *(float4*)(nf + (size_t)r * NEWS_DIM + d) = v;
        return;
    }
    i -= C_NV;
    if (i < C_LG) {                                  // logv -> lf_bf head
        float4 v = *(const float4*)(logv + (size_t)i * 4u);
        u32 e = i * 4u, r = e / IN_DIM, d = e - r * IN_DIM;
        *(uint2*)(lf_bf + (size_t)r * NEWS_DIM + d) = pack4(v);
        return;
    }
    i -= C_LG;
    if (i < C_PS) {                                  // pos rows 1..50 -> lf_bf tail
        u32 e = i * 4u, r = e / POS_DIM, d = e - r * POS_DIM;
        u32 h = r % HL_;
        float4 v = *(const float4*)(pos + (size_t)(1u + h) * POS_DIM + d);
        *(uint2*)(lf_bf + (size_t)r * NEWS_DIM + IN_DIM + d) = pack4(v);
        return;
    }
    i -= C_PS;
    if (i < C_NZ) {                                  // nf zero tail
        u32 e = i * 4u, r = e / POS_DIM, d = e - r * POS_DIM;
        *(float4*)(nf + (size_t)r * NEWS_DIM + IN_DIM + d) = make_float4(0.f, 0.f, 0.f, 0.f);
    }
}

// ---------------- K1: fused NT GEMMs, pure bf16 16B loads.
// bid < 256: pn[4096x256] = nv_bf . Wbf[:, :384]^T + b1
// bid >= 256: plT[(b*256+a)*50+h] = lf_bf . Wbf[:, 448:]^T  (transposed store)
__global__ __launch_bounds__(64) void gemm_k(
    const u16* __restrict__ nv_bf, const u16* __restrict__ lf_bf,
    const u16* __restrict__ Wbf, const float* __restrict__ b1,
    float* __restrict__ pn, float* __restrict__ plT)
{
    int bid = blockIdx.x;
    int lane = threadIdx.x;
    int m = lane & 15, q = lane >> 4;
    bool is_pn = bid < 256;
    int r0, c0, lda, koff, klen;
    const u16* A;
    if (is_pn) { r0 = (bid & 63) * 64;       c0 = (bid >> 6) * 64; A = nv_bf; lda = IN_DIM;   koff = 0;        klen = IN_DIM; }
    else { int b2 = bid - 256; r0 = (b2 % 50) * 64; c0 = (b2 / 50) * 64; A = lf_bf; lda = NEWS_DIM; koff = NEWS_DIM; klen = NEWS_DIM; }

    f32x4 acc[4][4];
#pragma unroll
    for (int a = 0; a < 4; a++)
#pragma unroll
        for (int b = 0; b < 4; b++) acc[a][b] = (f32x4){0.f, 0.f, 0.f, 0.f};

    const u16* Ap = A + (size_t)(r0 + m) * lda + q * 8;
    const u16* Wp = Wbf + (size_t)(c0 + m) * (2 * NEWS_DIM) + koff + q * 8;

    for (int k = 0; k < klen; k += 32) {
        short8 af[4], wf[4];
#pragma unroll
        for (int rt = 0; rt < 4; rt++) af[rt] = *(const short8*)(Ap + rt * 16 * lda + k);
#pragma unroll
        for (int ct = 0; ct < 4; ct++) wf[ct] = *(const short8*)(Wp + ct * 16 * (2 * NEWS_DIM) + k);
#pragma unroll
        for (int rt = 0; rt < 4; rt++)
#pragma unroll
            for (int ct = 0; ct < 4; ct++)
                acc[rt][ct] = __builtin_amdgcn_mfma_f32_16x16x32_bf16(
                    af[rt], wf[ct], acc[rt][ct], 0, 0, 0);
    }
    // C/D layout: col = lane&15, row = (lane>>4)*4 + i  [m89]
#pragma unroll
    for (int rt = 0; rt < 4; rt++)
#pragma unroll
        for (int ct = 0; ct < 4; ct++)
#pragma unroll
            for (int i = 0; i < 4; i++) {
                int gr = r0 + rt * 16 + q * 4 + i;
                int gc = c0 + ct * 16 + m;
                float v = acc[rt][ct][i];
                if (is_pn) {
                    pn[(size_t)gr * ATT_DIM + gc] = v + b1[gc];
                } else {
                    int bb = gr / HL_, hh = gr - bb * HL_;
                    plT[(size_t)(bb * ATT_DIM + gc) * HL_ + hh] = v;
                }
            }
}

// ---------------- K2: FUSED logits -> masked softmax -> out = attn x lf.
// One wave per (b, n-pair), lane = h for phase 1. Phase 2: same wave computes
// out[b,n,:] directly (lane covers d = lane+64j, j<7); attn passes through a
// per-wave LDS slice (no barrier needed: same-wave write/read).
__global__ __launch_bounds__(256) void attn_out_k(
    const float* __restrict__ pn, const float* __restrict__ plT,
    const float* __restrict__ w2, const int* __restrict__ lmask,
    const u16* __restrict__ lf_bf, float* __restrict__ out)
{
    __shared__ float at_s[4][2][64];           // per-wave slices, 2 KB
    int lane = threadIdx.x & 63;
    int wid = (int)(threadIdx.x >> 6);
    int g = blockIdx.x * 4 + wid;              // wave id in [0,2048)
    int b = g >> 5;
    int n0 = (g & 31) * 2;                     // n-pair
    int hl = (lane < HL_) ? lane : (HL_ - 1);  // clamp reads
    const float* pr0 = pn + ((size_t)b * NN_ + n0) * ATT_DIM;
    const float* pr1 = pr0 + ATT_DIM;
    const float* pl = plT + (size_t)b * ATT_DIM * HL_ + hl;

    float a00 = 0.f, a01 = 0.f, a10 = 0.f, a11 = 0.f;
#pragma unroll 2
    for (int a = 0; a < ATT_DIM; a += 4) {
        float4 w4 = *(const float4*)(w2 + a);
        float4 p0 = *(const float4*)(pr0 + a);
        float4 p1 = *(const float4*)(pr1 + a);
        float l0 = pl[(a + 0) * HL_];
        float l1 = pl[(a + 1) * HL_];
        float l2 = pl[(a + 2) * HL_];
        float l3 = pl[(a + 3) * HL_];
        a00 = __builtin_fmaf(fast_tanh(p0.x + l0), w4.x, a00);
        a10 = __builtin_fmaf(fast_tanh(p1.x + l0), w4.x, a10);
        a01 = __builtin_fmaf(fast_tanh(p0.y + l1), w4.y, a01);
        a11 = __builtin_fmaf(fast_tanh(p1.y + l1), w4.y, a11);
        a00 = __builtin_fmaf(fast_tanh(p0.z + l2), w4.z, a00);
        a10 = __builtin_fmaf(fast_tanh(p1.z + l2), w4.z, a10);
        a01 = __builtin_fmaf(fast_tanh(p0.w + l3), w4.w, a01);
        a11 = __builtin_fmaf(fast_tanh(p1.w + l3), w4.w, a11);
    }
    float acc0 = a00 + a01, acc1 = a10 + a11;
    int mv = (lane < HL_) ? lmask[b * HL_ + lane] : 0;
    float lg0 = mv ? acc0 : -1e9f;             // b2 dropped: softmax-invariant
    float lg1 = mv ? acc1 : -1e9f;
    float mx0 = lg0, mx1 = lg1;
#pragma unroll
    for (int o = 32; o > 0; o >>= 1) {
        mx0 = fmaxf(mx0, __shfl_xor(mx0, o));
        mx1 = fmaxf(mx1, __shfl_xor(mx1, o));
    }
    float e0 = EXP2F((lg0 - mx0) * 1.44269504f);   // masked lanes -> 0
    float e1 = EXP2F((lg1 - mx1) * 1.44269504f);
    float s0 = e0, s1 = e1;
#pragma unroll
    for (int o = 32; o > 0; o >>= 1) {
        s0 += __shfl_xor(s0, o);
        s1 += __shfl_xor(s1, o);
    }
    at_s[wid][0][lane] = e0 * RCPF(s0);
    at_s[wid][1][lane] = e1 * RCPF(s1);
    // no __syncthreads: same wave writes & reads its slice (lgkmcnt enforced)

    // phase 2: out[b, n0+n][d], d = lane + 64j (j<7); lf rows coalesced 128B.
    const u16* lfb = lf_bf + (size_t)b * HL_ * NEWS_DIM + lane;
    float acc[2][7];
#pragma unroll
    for (int j = 0; j < 7; j++) { acc[0][j] = 0.f; acc[1][j] = 0.f; }
    for (int h = 0; h < HL_; h++) {
        float v0 = at_s[wid][0][h];            // LDS broadcast
        float v1 = at_s[wid][1][h];
        const u16* row = lfb + (size_t)h * NEWS_DIM;
#pragma unroll
        for (int j = 0; j < 7; j++) {
            float lv = bf2f(row[64 * j]);
            acc[0][j] = fmaf(v0, lv, acc[0][j]);
            acc[1][j] = fmaf(v1, lv, acc[1][j]);
        }
    }
    float* o0 = out + ((size_t)b * NN_ + n0) * NEWS_DIM + lane;
#pragma unroll
    for (int j = 0; j < 7; j++) {
        o0[64 * j] = acc[0][j];
        o0[NEWS_DIM + 64 * j] = acc[1][j];
    }
}

extern "C" void kernel_launch(void* const* d_in, const int* in_sizes, int n_in,
                              void* d_out, int out_size, void* d_ws, size_t ws_size,
                              hipStream_t stream) {
    const float* logv  = (const float*)d_in[0];  // (64,50,384) f32
    const int*   lmask = (const int*)d_in[1];    // (64,50) i32
    const float* newsv = (const float*)d_in[2];  // (64,64,384) f32
    const float* pos   = (const float*)d_in[3];  // (100,64) f32; row 0 == 0
    const float* W1    = (const float*)d_in[4];  // (256,896) f32
    const float* b1    = (const float*)d_in[5];  // (256,) f32
    const float* w2    = (const float*)d_in[6];  // (1,256) f32
    // b2 unused (softmax-invariant shift)

    float* out = (float*)d_out;                  // [user_log | nf], f32
    float* nf  = out + (size_t)B_ * NN_ * NEWS_DIM;

    // d_ws ~256 MiB. Byte offsets, 16B aligned:
    char* ws = (char*)d_ws;
    u16*   lf_bf = (u16*)(ws + 0);               // 3200x448 bf16  (2,867,200 B)
    u16*   Wbf   = (u16*)(ws + 2867200);         // 256x896 bf16   (458,752 B)
    u16*   nv_bf = (u16*)(ws + 3325952);         // 4096x384 bf16  (3,145,728 B)
    float* pn    = (float*)(ws + 6471680);       // 4096x256 f32   (4,194,304 B)
    float* plT   = (float*)(ws + 10665984);      // 64x256x50 f32  (3,276,800 B)

    prep_k    <<<C_TOT / 256, 256, 0, stream>>>(W1, newsv, logv, pos,
                                                Wbf, nv_bf, lf_bf, nf);
    gemm_k    <<<456, 64, 0, stream>>>(nv_bf, lf_bf, Wbf, b1, pn, plT);
    attn_out_k<<<512, 256, 0, stream>>>(pn, plT, w2, lmask, lf_bf, out);
}